// Round 9
// baseline (172.246 us; speedup 1.0000x reference)
//
#include <hip/hip_runtime.h>
#include <hip/hip_bf16.h>

// ---------------------------------------------------------------------------
// OuterProductMean (AlphaFold) fused MFMA implementation for gfx950.
//   B=1, N=128 (MSA depth), L=256, C_M=256, C_H=32, C_Z=128
// Pipeline (3 launches):
//   k_prep    : [Wa|Wb] fp32 -> WT bf16 [64][256] (h-major, c contiguous)
//   k_ln_proj : main blocks: LayerNorm + a/b projection (MFMA) -> aT/bT bf16
//               [8192][128] (row = l*32+h, col = MSA index n -> K-contiguous).
//               tail: W2 = Wo bf16 fragment-sequential; pm_recip.
//   k_outer   : v9 — 8i x 8j tile, grid 1024, 128KB LDS, single-pass stage 2.
//               History: v6 (two kh-half transposes, 64KB) = 55.5us clean.
//               v7/v8 (32,32)-retile halved stage-2 LDS reads (bank-conflict
//               cycles -40%) but BOTH spilled (+14MB scratch writes): during
//               GEMM kh=0 half of acc[8][4] stayed live (needed by kh=1's
//               transpose) on top of ring+acc2 -> over the 2-wave/SIMD cap.
//               v9: O2 for ALL 64 pairs in 128KB LDS -> ONE transpose phase,
//               acc fully dead before the single 32-iter GEMM; keeps the
//               (32,32) retile (512KB stage-2 reads) + depth-8 two-stream W2
//               ring preloaded under the transpose; one fewer barrier pair.
// ---------------------------------------------------------------------------

typedef __attribute__((ext_vector_type(8))) short bf8_t;   // 8 x bf16 (4 VGPRs)
typedef __attribute__((ext_vector_type(4))) float f32x4;   // MFMA accumulator

__device__ __forceinline__ unsigned short f2bf(float f) {
    unsigned int u = __float_as_uint(f);
    u += 0x7fffu + ((u >> 16) & 1u);        // RNE (finite values only)
    return (unsigned short)(u >> 16);
}
__device__ __forceinline__ unsigned int pack2(float a, float b) {
    return (unsigned int)f2bf(a) | ((unsigned int)f2bf(b) << 16);
}

// async 16B global -> LDS (dest = wave-uniform base + lane*16, linear)
__device__ __forceinline__ void cp16_async(const void* g, void* l) {
    __builtin_amdgcn_global_load_lds(
        (const __attribute__((address_space(1))) unsigned int*)g,
        (__attribute__((address_space(3))) unsigned int*)l, 16, 0, 0);
}

// ---------------------------------------------------------------------------
// WT[h][c] = (h<32 ? Wa[c][h] : Wb[c][h-32]), bf16. 16384 elems, 64 blocks.
__global__ __launch_bounds__(256) void k_prep(const float* __restrict__ Wa,
                                              const float* __restrict__ Wb,
                                              unsigned short* __restrict__ WTb) {
    int u = blockIdx.x * 256 + threadIdx.x;          // u = h*256 + c
    int h = u >> 8, c = u & 255;
    float v = (h < 32) ? Wa[c * 32 + h] : Wb[c * 32 + (h - 32)];
    WTb[u] = f2bf(v);
}

// ---------------------------------------------------------------------------
// Blocks [0,2048): LayerNorm + projection. Blocks [2048,2560): W2 build.
// Blocks [2560,2816): pair-mask reciprocal.
__global__ __launch_bounds__(256) void k_ln_proj(
    const float* __restrict__ gm, const float* __restrict__ gmask,
    const float* __restrict__ gamma, const float* __restrict__ beta,
    const unsigned short* __restrict__ WTb,
    const float* __restrict__ ba, const float* __restrict__ bb,
    const float* __restrict__ Wo,
    unsigned short* __restrict__ aT, unsigned short* __restrict__ bT,
    unsigned short* __restrict__ W2, float* __restrict__ pmr)
{
    const int tid = threadIdx.x;
    const int tail = (int)blockIdx.x - 2048;
    if (tail >= 0) {
        if (tail < 512) {
            // W2 fragment-sequential: (zt=z>>4, s=k'>>5, r16=z&15, kg=(k'>>3)&3, e=k'&7)
            // with k' = d*32+c, Wo element index u = (c*32+d)*128 + z.
            int u = tail * 256 + tid;                // u = k*128 + z (coalesced read)
            int k = u >> 7, z = u & 127;
            int c = k >> 5, d = k & 31;
            int kp = d * 32 + c;
            int dst = (((z >> 4) * 32 + (kp >> 5)) * 16 + (z & 15)) * 32
                      + ((kp >> 3) & 3) * 8 + (kp & 7);
            W2[dst] = f2bf(Wo[u]);
        } else {
            int u = (tail - 512) * 256 + tid;        // u = i*256 + j
            int i = u >> 8, j = u & 255;
            float s = 0.f;
            #pragma unroll 8
            for (int n = 0; n < 128; n++)
                s += gmask[n * 256 + i] * gmask[n * 256 + j];
            pmr[u] = 1.f / (s + 1e-8f);
        }
        return;
    }

    __shared__ __align__(16) unsigned short xlb[16 * 256]; // [row][c] bf16, swizzled
    __shared__ float vl[16 * 64];                          // [n-row][h]
    const int lane = tid & 63, w = tid >> 6;
    const int l = blockIdx.x & 255, n0 = ((int)blockIdx.x >> 8) << 4;

    const float4 g4  = ((const float4*)gamma)[lane];
    const float4 be4 = ((const float4*)beta)[lane];

    // ---- phase 1: LN (wave per row, 4 rows per wave) ----
    #pragma unroll
    for (int j = 0; j < 4; j++) {
        int row = w * 4 + j;
        int n = n0 + row;
        float4 v = ((const float4*)(gm + ((size_t)n * 256 + l) * 256))[lane];
        float s = v.x + v.y + v.z + v.w;
        float q = v.x * v.x + v.y * v.y + v.z * v.z + v.w * v.w;
        #pragma unroll
        for (int off = 1; off < 64; off <<= 1) {
            s += __shfl_xor(s, off);
            q += __shfl_xor(q, off);
        }
        float mean = s * (1.f / 256.f);
        float var = fmaxf(q * (1.f / 256.f) - mean * mean, 0.f);
        float rstd = rsqrtf(var + 1e-5f);
        float x0 = (v.x - mean) * rstd * g4.x + be4.x;
        float x1 = (v.y - mean) * rstd * g4.y + be4.y;
        float x2 = (v.z - mean) * rstd * g4.z + be4.z;
        float x3 = (v.w - mean) * rstd * g4.w + be4.w;
        int c8s = lane ^ ((row & 7) << 1);               // 8B-chunk XOR swizzle
        *(uint2*)((char*)xlb + row * 512 + (c8s << 3)) =
            make_uint2(pack2(x0, x1), pack2(x2, x3));
    }
    __syncthreads();

    // ---- phase 2: projection via MFMA (wave w -> h-cols w*16..w*16+15) ----
    const int kg = lane >> 4, r16 = lane & 15;
    const int h = w * 16 + r16;
    f32x4 acc = {0.f, 0.f, 0.f, 0.f};
    #pragma unroll
    for (int ks = 0; ks < 8; ks++) {
        int c8 = ks * 8 + kg * 2;                        // even -> 16B pair intact
        bf8_t af = *(const bf8_t*)((char*)xlb + r16 * 512 +
                                   ((c8 ^ ((r16 & 7) << 1)) << 3));
        bf8_t wf = *(const bf8_t*)(WTb + (size_t)h * 256 + ks * 32 + kg * 8);
        acc = __builtin_amdgcn_mfma_f32_16x16x32_bf16(af, wf, acc, 0, 0, 0);
    }
    float bias = (h < 32) ? ba[h] : bb[h - 32];
    #pragma unroll
    for (int r = 0; r < 4; r++) {
        int nrow = kg * 4 + r;                           // C/D row = MSA row index
        float mk = gmask[(size_t)(n0 + nrow) * 256 + l];
        vl[nrow * 64 + h] = (acc[r] + bias) * mk;
    }
    __syncthreads();

    // ---- phase 3: repack, 8 n-values per thread, 16B stores ----
    if (tid < 128) {
        int row = tid >> 1, half = tid & 1;              // row = h index 0..63
        int hh = row & 31;
        unsigned short* dst = (row < 32) ? aT : bT;
        unsigned int pk[4];
        #pragma unroll
        for (int jj = 0; jj < 4; jj++)
            pk[jj] = pack2(vl[(half * 8 + 2 * jj) * 64 + row],
                           vl[(half * 8 + 2 * jj + 1) * 64 + row]);
        *(uint4*)(dst + ((size_t)l * 32 + hh) * 128 + n0 + half * 8) =
            make_uint4(pk[0], pk[1], pk[2], pk[3]);
    }
}

// ---------------------------------------------------------------------------
// Fused outer-product + Wo projection, v9.
// Grid 1024 = 32 tj (fast) x 32 ti. 512 thr = 8 waves; 128KB LDS; 1 block/CU.
// Stage 1: 256(i.h) x 256(j.h) outer tile, K=128 in two halves of 64.
//   Wave grid 2(wr) x 4(wc) -> per-wave 128x64 -> acc[8][4] (128 AGPR).
//   Staging: global_load_lds w=16, source pre-swizzled (LDS linear);
//   A 32KB @0 + B 32KB @32768 per half (first 64KB of smem).
// Stage 2 (single pass): transpose ALL accs -> O2[64 pairs][1024 k2] bf16
//   (128KB, overwrites staging; acc then DEAD) -> one 32-iter GEMM.
//   Wave grid 2(mg: 32 pairs) x 4(zg: 32 z); per wave 2x2 16-tiles.
//   A-LDS reads 512KB/block; W2 via two-stream depth-8 ring preloaded
//   under the transpose.
__global__ __launch_bounds__(512, 2) void k_outer(
    const unsigned short* __restrict__ aT, const unsigned short* __restrict__ bT,
    const unsigned short* __restrict__ W2, const float* __restrict__ pmr,
    const float* __restrict__ bo, float* __restrict__ out)
{
    __shared__ __align__(16) char smem[131072];
    const int tid = threadIdx.x, lane = tid & 63, w = tid >> 6;   // 8 waves
    const int wr = w >> 2, wc = w & 3;                  // stage-1: 2 x 4 wave grid
    const int mg = w >> 2, zg = w & 3;                  // stage-2: 2 x 4 wave grid
    const int tj = blockIdx.x & 31, ti = blockIdx.x >> 5;         // 32 x 32
    const int kg = lane >> 4, r16 = lane & 15;

    f32x4 acc[8][4];
    #pragma unroll
    for (int mt = 0; mt < 8; mt++)
        #pragma unroll
        for (int nt = 0; nt < 4; nt++)
            acc[mt][nt] = (f32x4){0.f, 0.f, 0.f, 0.f};

    const uint4* gA = (const uint4*)(aT + (size_t)ti * 32768);    // 8i x 32h x 128n
    const uint4* gB = (const uint4*)(bT + (size_t)tj * 32768);    // 8j x 32h x 128n

    // ---- stage 1: two K=64 halves; A 32KB @0, B 32KB @32768 ----
    #pragma unroll
    for (int half = 0; half < 2; half++) {
        // async stage: LDS[row][c] = global chunk (c ^ (row&7))  (read undoes XOR)
        #pragma unroll
        for (int t = 0; t < 4; t++) {                    // A: 2048 chunks / 8w / 64l
            int q = w * 256 + t * 64 + lane;
            int row = q >> 3, c = q & 7;
            cp16_async(gA + row * 16 + half * 8 + (c ^ (row & 7)),
                       smem + (q << 4) - (lane << 4));   // wave-uniform base
        }
        #pragma unroll
        for (int t = 0; t < 4; t++) {                    // B: 2048 chunks
            int q = w * 256 + t * 64 + lane;
            int row = q >> 3, c = q & 7;
            cp16_async(gB + row * 16 + half * 8 + (c ^ (row & 7)),
                       smem + 32768 + (q << 4) - (lane << 4));
        }
        __syncthreads();                                  // staging drained here

        #pragma unroll
        for (int ks2 = 0; ks2 < 2; ks2++) {
            int ch = ks2 * 4 + kg;
            bf8_t af[8];
            #pragma unroll
            for (int mt = 0; mt < 8; mt++) {
                int mm = wr * 128 + mt * 16 + r16;
                af[mt] = *(const bf8_t*)(smem + mm * 128 + ((ch ^ (mm & 7)) << 4));
            }
            #pragma unroll
            for (int nt = 0; nt < 4; nt++) {
                int nn = wc * 64 + nt * 16 + r16;
                bf8_t bfr = *(const bf8_t*)(smem + 32768 + nn * 128 +
                                            ((ch ^ (nn & 7)) << 4));
                #pragma unroll
                for (int mt = 0; mt < 8; mt++)
                    acc[mt][nt] = __builtin_amdgcn_mfma_f32_16x16x32_bf16(
                        af[mt], bfr, acc[mt][nt], 0, 0, 0);
            }
        }
        __syncthreads();   // LDS free for next half / the transpose
    }

    // ---- stage 2, single pass ----
    // O2[p][k2]: p = i_loc*8 + j_loc (64 pairs), k2 = (nn&31)*32 + (mm&31)
    // (1024 per row = 2KB). chunk c2 = k2>>3 (0..127);
    // swizzle pc = c2 ^ ((c2>>3)&7) ^ (p&7)  (bijective per p; spreads banks).
    unsigned short* O2b = (unsigned short*)smem;        // 64 x 1024 bf16 = 128 KB
    const int psw = r16 & 7;
    // two W2 fragment streams: z-tiles zg*2 and zg*2+1
    const unsigned short* wz0 = W2 + (size_t)(zg * 2) * 16384 + r16 * 32 + kg * 8;
    const unsigned short* wz1 = wz0 + 16384;

#define W2LDA(x) (*(const bf8_t*)(wz0 + (x) * 512))
#define W2LDB(x) (*(const bf8_t*)(wz1 + (x) * 512))
    // depth-8 two-stream ring preload: 16 loads fly under the transpose
    bf8_t w0 = W2LDA(0), w1 = W2LDA(1), w2 = W2LDA(2), w3 = W2LDA(3);
    bf8_t w4 = W2LDA(4), w5 = W2LDA(5), w6 = W2LDA(6), w7 = W2LDA(7);
    bf8_t x0 = W2LDB(0), x1 = W2LDB(1), x2 = W2LDB(2), x3 = W2LDB(3);
    bf8_t x4 = W2LDB(4), x5 = W2LDB(5), x6 = W2LDB(6), x7 = W2LDB(7);

    // transpose ALL accs -> O2 (acc C/D: row = kg*4+r, col = r16); acc dead after.
    #pragma unroll
    for (int mt = 0; mt < 8; mt++) {
        #pragma unroll
        for (int nt = 0; nt < 4; nt++) {
            int p  = (wr * 4 + (mt >> 1)) * 8 + (wc * 2 + (nt >> 1));
            int k2 = ((nt & 1) * 16 + r16) * 32 + ((mt & 1) << 4) + kg * 4; // +r
            int c2 = k2 >> 3;
            int pc = c2 ^ ((c2 >> 3) & 7) ^ (p & 7);
            *(uint2*)(O2b + p * 1024 + pc * 8 + (k2 & 7)) =
                make_uint2(pack2(acc[mt][nt][0], acc[mt][nt][1]),
                           pack2(acc[mt][nt][2], acc[mt][nt][3]));
        }
    }
    __syncthreads();

    // GEMM: Z[64,128] = O2[64,1024] @ W2[1024,128]; 32 K-chunks, ring slot =
    // sl & 7, lookahead 8 (prefetch while sl < 24).
    f32x4 acc2_00 = {0.f,0.f,0.f,0.f}, acc2_01 = {0.f,0.f,0.f,0.f};
    f32x4 acc2_10 = {0.f,0.f,0.f,0.f}, acc2_11 = {0.f,0.f,0.f,0.f};
    // A rows mg*32+r16 (m-tile 0) and +16 (m-tile 1); (row&7)==psw for both.
    const unsigned short* O2r = O2b + (mg * 32 + r16) * 1024;

// Snapshot BEFORE prefetch overwrites the ring regs (v4 lesson). sl literal.
#define S2R(sl, wa, xa, PF)                                                   \
    {                                                                         \
        bf8_t wca = wa, wcb = xa;                                             \
        PF;                                                                   \
        int c2 = (sl) * 4 + kg;                                               \
        int pc = c2 ^ ((c2 >> 3) & 7) ^ psw;                                  \
        const unsigned short* ar = O2r + pc * 8;                              \
        bf8_t a0 = *(const bf8_t*)(ar);                                       \
        bf8_t a1 = *(const bf8_t*)(ar + 16 * 1024);                           \
        acc2_00 = __builtin_amdgcn_mfma_f32_16x16x32_bf16(a0, wca, acc2_00,   \
                                                          0, 0, 0);           \
        acc2_01 = __builtin_amdgcn_mfma_f32_16x16x32_bf16(a0, wcb, acc2_01,   \
                                                          0, 0, 0);           \
        acc2_10 = __builtin_amdgcn_mfma_f32_16x16x32_bf16(a1, wca, acc2_10,   \
                                                          0, 0, 0);           \
        acc2_11 = __builtin_amdgcn_mfma_f32_16x16x32_bf16(a1, wcb, acc2_11,   \
                                                          0, 0, 0);           \
    }

    S2R(0,  w0, x0, { w0 = W2LDA(8);  x0 = W2LDB(8);  })
    S2R(1,  w1, x1, { w1 = W2LDA(9);  x1 = W2LDB(9);  })
    S2R(2,  w2, x2, { w2 = W2LDA(10); x2 = W2LDB(10); })
    S2R(3,  w3, x3, { w3 = W2LDA(11); x3 = W2LDB(11); })
    S2R(4,  w4, x4, { w4 = W2LDA(12); x4 = W2LDB(12); })
    S2R(5,  w5, x5, { w5 = W2LDA(13); x5 = W2LDB(13); })
    S2R(6,  w6, x6, { w6 = W2LDA(14); x6 = W2LDB(14); })
    S2R(7,  w7, x7, { w7 = W2LDA(15); x7 = W2LDB(15); })
    S2R(8,  w0, x0, { w0 = W2LDA(16); x0 = W2LDB(16); })
    S2R(9,  w1, x1, { w1 = W2LDA(17); x1 = W2LDB(17); })
    S2R(10, w2, x2, { w2 = W2LDA(18); x2 = W2LDB(18); })
    S2R(11, w3, x3, { w3 = W2LDA(19); x3 = W2LDB(19); })
    S2R(12, w4, x4, { w4 = W2LDA(20); x4 = W2LDB(20); })
    S2R(13, w5, x5, { w5 = W2LDA(21); x5 = W2LDB(21); })
    S2R(14, w6, x6, { w6 = W2LDA(22); x6 = W2LDB(22); })
    S2R(15, w7, x7, { w7 = W2LDA(23); x7 = W2LDB(23); })
    S2R(16, w0, x0, { w0 = W2LDA(24); x0 = W2LDB(24); })
    S2R(17, w1, x1, { w1 = W2LDA(25); x1 = W2LDB(25); })
    S2R(18, w2, x2, { w2 = W2LDA(26); x2 = W2LDB(26); })
    S2R(19, w3, x3, { w3 = W2LDA(27); x3 = W2LDB(27); })
    S2R(20, w4, x4, { w4 = W2LDA(28); x4 = W2LDB(28); })
    S2R(21, w5, x5, { w5 = W2LDA(29); x5 = W2LDB(29); })
    S2R(22, w6, x6, { w6 = W2LDA(30); x6 = W2LDB(30); })
    S2R(23, w7, x7, { w7 = W2LDA(31); x7 = W2LDB(31); })
    S2R(24, w0, x0, {})
    S2R(25, w1, x1, {})
    S2R(26, w2, x2, {})
    S2R(27, w3, x3, {})
    S2R(28, w4, x4, {})
    S2R(29, w5, x5, {})
    S2R(30, w6, x6, {})
    S2R(31, w7, x7, {})
#undef S2R
#undef W2LDA
#undef W2LDB

    // ---- epilogue: scale by 1/(pair_mask+eps), add bias, store ----
    // acc2_mn: m = pair-tile (rows mg*32+m*16), n = z-tile (z = (zg*2+n)*16+r16)
    const int i0 = ti * 8, j0 = tj * 8;
    const float boz0 = bo[(zg * 2) * 16 + r16];
    const float boz1 = bo[(zg * 2 + 1) * 16 + r16];
    #pragma unroll
    for (int m = 0; m < 2; m++)
        #pragma unroll
        for (int r = 0; r < 4; r++) {
            int p = mg * 32 + m * 16 + kg * 4 + r;
            int i = i0 + (p >> 3), j = j0 + (p & 7);
            float recip = pmr[i * 256 + j];
            size_t o = ((size_t)(i * 256 + j)) * 128;
            float v0 = (m ? acc2_10[r] : acc2_00[r]) * recip + boz0;
            float v1 = (m ? acc2_11[r] : acc2_01[r]) * recip + boz1;
            out[o + (zg * 2) * 16 + r16]     = v0;
            out[o + (zg * 2 + 1) * 16 + r16] = v1;
        }
}

// ---------------------------------------------------------------------------
extern "C" void kernel_launch(void* const* d_in, const int* in_sizes, int n_in,
                              void* d_out, int out_size, void* d_ws, size_t ws_size,
                              hipStream_t stream)
{
    const float* m    = (const float*)d_in[0];
    const float* mask = (const float*)d_in[1];
    const float* gam  = (const float*)d_in[2];
    const float* bet  = (const float*)d_in[3];
    const float* Wa   = (const float*)d_in[4];
    const float* ba   = (const float*)d_in[5];
    const float* Wb   = (const float*)d_in[6];
    const float* bb   = (const float*)d_in[7];
    const float* Wo   = (const float*)d_in[8];
    const float* bo   = (const float*)d_in[9];
    float* out = (float*)d_out;

    unsigned short* aT  = (unsigned short*)d_ws;           // 8192*128 bf16 = 2 MB
    unsigned short* bT  = aT + 8192 * 128;                 // 2 MB
    unsigned short* W2  = bT + 8192 * 128;                 // 128*1024 bf16 = 256 KB
    unsigned short* WTb = W2 + 128 * 1024;                 // 64*256 bf16 = 32 KB
    float* pmr = (float*)(WTb + 64 * 256);                 // 256*256 fp32 = 256 KB

    k_prep   <<<  64, 256, 0, stream>>>(Wa, Wb, WTb);
    k_ln_proj<<<2816, 256, 0, stream>>>(m, mask, gam, bet, WTb, ba, bb, Wo,
                                        aT, bT, W2, pmr);
    k_outer  <<<1024, 512, 0, stream>>>(aT, bT, W2, pmr, bo, out);
}

// Round 10
// 167.466 us; speedup vs baseline: 1.0285x; 1.0285x over previous
//
#include <hip/hip_runtime.h>
#include <hip/hip_bf16.h>

// ---------------------------------------------------------------------------
// OuterProductMean (AlphaFold) fused MFMA implementation for gfx950.
//   B=1, N=128 (MSA depth), L=256, C_M=256, C_H=32, C_Z=128
// Pipeline (3 launches):
//   k_prep    : [Wa|Wb] fp32 -> WT bf16 [64][256] (h-major, c contiguous)
//   k_ln_proj : main blocks: LayerNorm + a/b projection (MFMA) -> aT/bT bf16
//               [8192][128] (row = l*32+h, col = MSA index n -> K-contiguous).
//               tail: W2 = Wo bf16 fragment-sequential; pm_recip.
//   k_outer   : v10 — v9 (8i x 8j, grid 1024, 128KB LDS, single-pass stage-2,
//               (32,32) stage-2 retile) with the W2 ring cut from 64 to 16
//               VGPRs (two-stream DEPTH-2).
//               Register invariant (R7-R9 lesson): acc[8][4] = 128 AGPR pins
//               the VGPR side at 128 (unified file, 2 waves/SIMD = 256 cap).
//               v7/v8/v9 all spilled by exceeding it (ring 64 / kh-liveness /
//               ring-64-before-transpose). R4 proved stage 2 is NOT latency
//               bound -> ring depth is irrelevant; depth-2 is free.
//               Retile mechanism is counter-verified: bank-conflict cycles
//               -40% (5.24M -> 3.15M) in v7/v8/v9; stage-2 ds_read is the
//               biggest LDS-port consumer (~12.3k cy/block of ~19k total).
// ---------------------------------------------------------------------------

typedef __attribute__((ext_vector_type(8))) short bf8_t;   // 8 x bf16 (4 VGPRs)
typedef __attribute__((ext_vector_type(4))) float f32x4;   // MFMA accumulator

__device__ __forceinline__ unsigned short f2bf(float f) {
    unsigned int u = __float_as_uint(f);
    u += 0x7fffu + ((u >> 16) & 1u);        // RNE (finite values only)
    return (unsigned short)(u >> 16);
}
__device__ __forceinline__ unsigned int pack2(float a, float b) {
    return (unsigned int)f2bf(a) | ((unsigned int)f2bf(b) << 16);
}

// async 16B global -> LDS (dest = wave-uniform base + lane*16, linear)
__device__ __forceinline__ void cp16_async(const void* g, void* l) {
    __builtin_amdgcn_global_load_lds(
        (const __attribute__((address_space(1))) unsigned int*)g,
        (__attribute__((address_space(3))) unsigned int*)l, 16, 0, 0);
}

// ---------------------------------------------------------------------------
// WT[h][c] = (h<32 ? Wa[c][h] : Wb[c][h-32]), bf16. 16384 elems, 64 blocks.
__global__ __launch_bounds__(256) void k_prep(const float* __restrict__ Wa,
                                              const float* __restrict__ Wb,
                                              unsigned short* __restrict__ WTb) {
    int u = blockIdx.x * 256 + threadIdx.x;          // u = h*256 + c
    int h = u >> 8, c = u & 255;
    float v = (h < 32) ? Wa[c * 32 + h] : Wb[c * 32 + (h - 32)];
    WTb[u] = f2bf(v);
}

// ---------------------------------------------------------------------------
// Blocks [0,2048): LayerNorm + projection. Blocks [2048,2560): W2 build.
// Blocks [2560,2816): pair-mask reciprocal.
__global__ __launch_bounds__(256) void k_ln_proj(
    const float* __restrict__ gm, const float* __restrict__ gmask,
    const float* __restrict__ gamma, const float* __restrict__ beta,
    const unsigned short* __restrict__ WTb,
    const float* __restrict__ ba, const float* __restrict__ bb,
    const float* __restrict__ Wo,
    unsigned short* __restrict__ aT, unsigned short* __restrict__ bT,
    unsigned short* __restrict__ W2, float* __restrict__ pmr)
{
    const int tid = threadIdx.x;
    const int tail = (int)blockIdx.x - 2048;
    if (tail >= 0) {
        if (tail < 512) {
            // W2 fragment-sequential: (zt=z>>4, s=k'>>5, r16=z&15, kg=(k'>>3)&3, e=k'&7)
            // with k' = d*32+c, Wo element index u = (c*32+d)*128 + z.
            int u = tail * 256 + tid;                // u = k*128 + z (coalesced read)
            int k = u >> 7, z = u & 127;
            int c = k >> 5, d = k & 31;
            int kp = d * 32 + c;
            int dst = (((z >> 4) * 32 + (kp >> 5)) * 16 + (z & 15)) * 32
                      + ((kp >> 3) & 3) * 8 + (kp & 7);
            W2[dst] = f2bf(Wo[u]);
        } else {
            int u = (tail - 512) * 256 + tid;        // u = i*256 + j
            int i = u >> 8, j = u & 255;
            float s = 0.f;
            #pragma unroll 8
            for (int n = 0; n < 128; n++)
                s += gmask[n * 256 + i] * gmask[n * 256 + j];
            pmr[u] = 1.f / (s + 1e-8f);
        }
        return;
    }

    __shared__ __align__(16) unsigned short xlb[16 * 256]; // [row][c] bf16, swizzled
    __shared__ float vl[16 * 64];                          // [n-row][h]
    const int lane = tid & 63, w = tid >> 6;
    const int l = blockIdx.x & 255, n0 = ((int)blockIdx.x >> 8) << 4;

    const float4 g4  = ((const float4*)gamma)[lane];
    const float4 be4 = ((const float4*)beta)[lane];

    // ---- phase 1: LN (wave per row, 4 rows per wave) ----
    #pragma unroll
    for (int j = 0; j < 4; j++) {
        int row = w * 4 + j;
        int n = n0 + row;
        float4 v = ((const float4*)(gm + ((size_t)n * 256 + l) * 256))[lane];
        float s = v.x + v.y + v.z + v.w;
        float q = v.x * v.x + v.y * v.y + v.z * v.z + v.w * v.w;
        #pragma unroll
        for (int off = 1; off < 64; off <<= 1) {
            s += __shfl_xor(s, off);
            q += __shfl_xor(q, off);
        }
        float mean = s * (1.f / 256.f);
        float var = fmaxf(q * (1.f / 256.f) - mean * mean, 0.f);
        float rstd = rsqrtf(var + 1e-5f);
        float x0 = (v.x - mean) * rstd * g4.x + be4.x;
        float x1 = (v.y - mean) * rstd * g4.y + be4.y;
        float x2 = (v.z - mean) * rstd * g4.z + be4.z;
        float x3 = (v.w - mean) * rstd * g4.w + be4.w;
        int c8s = lane ^ ((row & 7) << 1);               // 8B-chunk XOR swizzle
        *(uint2*)((char*)xlb + row * 512 + (c8s << 3)) =
            make_uint2(pack2(x0, x1), pack2(x2, x3));
    }
    __syncthreads();

    // ---- phase 2: projection via MFMA (wave w -> h-cols w*16..w*16+15) ----
    const int kg = lane >> 4, r16 = lane & 15;
    const int h = w * 16 + r16;
    f32x4 acc = {0.f, 0.f, 0.f, 0.f};
    #pragma unroll
    for (int ks = 0; ks < 8; ks++) {
        int c8 = ks * 8 + kg * 2;                        // even -> 16B pair intact
        bf8_t af = *(const bf8_t*)((char*)xlb + r16 * 512 +
                                   ((c8 ^ ((r16 & 7) << 1)) << 3));
        bf8_t wf = *(const bf8_t*)(WTb + (size_t)h * 256 + ks * 32 + kg * 8);
        acc = __builtin_amdgcn_mfma_f32_16x16x32_bf16(af, wf, acc, 0, 0, 0);
    }
    float bias = (h < 32) ? ba[h] : bb[h - 32];
    #pragma unroll
    for (int r = 0; r < 4; r++) {
        int nrow = kg * 4 + r;                           // C/D row = MSA row index
        float mk = gmask[(size_t)(n0 + nrow) * 256 + l];
        vl[nrow * 64 + h] = (acc[r] + bias) * mk;
    }
    __syncthreads();

    // ---- phase 3: repack, 8 n-values per thread, 16B stores ----
    if (tid < 128) {
        int row = tid >> 1, half = tid & 1;              // row = h index 0..63
        int hh = row & 31;
        unsigned short* dst = (row < 32) ? aT : bT;
        unsigned int pk[4];
        #pragma unroll
        for (int jj = 0; jj < 4; jj++)
            pk[jj] = pack2(vl[(half * 8 + 2 * jj) * 64 + row],
                           vl[(half * 8 + 2 * jj + 1) * 64 + row]);
        *(uint4*)(dst + ((size_t)l * 32 + hh) * 128 + n0 + half * 8) =
            make_uint4(pk[0], pk[1], pk[2], pk[3]);
    }
}

// ---------------------------------------------------------------------------
// Fused outer-product + Wo projection, v10.
// Grid 1024 = 32 tj (fast) x 32 ti. 512 thr = 8 waves; 128KB LDS; 1 block/CU.
// Stage 1: 256(i.h) x 256(j.h) outer tile, K=128 in two halves of 64.
//   Wave grid 2(wr) x 4(wc) -> per-wave 128x64 -> acc[8][4] (128 AGPR).
//   Staging: global_load_lds w=16, source pre-swizzled (LDS linear);
//   A 32KB @0 + B 32KB @32768 per half (first 64KB of smem).
// Stage 2 (single pass): transpose ALL accs -> O2[64 pairs][1024 k2] bf16
//   (128KB; acc then DEAD) -> one 32-iter GEMM.
//   Wave grid 2(mg: 32 pairs) x 4(zg: 32 z); per wave 2x2 16-tiles.
//   A-LDS reads 512KB/block; W2 via two-stream DEPTH-2 ring (16 VGPR).
__global__ __launch_bounds__(512, 2) void k_outer(
    const unsigned short* __restrict__ aT, const unsigned short* __restrict__ bT,
    const unsigned short* __restrict__ W2, const float* __restrict__ pmr,
    const float* __restrict__ bo, float* __restrict__ out)
{
    __shared__ __align__(16) char smem[131072];
    const int tid = threadIdx.x, lane = tid & 63, w = tid >> 6;   // 8 waves
    const int wr = w >> 2, wc = w & 3;                  // stage-1: 2 x 4 wave grid
    const int mg = w >> 2, zg = w & 3;                  // stage-2: 2 x 4 wave grid
    const int tj = blockIdx.x & 31, ti = blockIdx.x >> 5;         // 32 x 32
    const int kg = lane >> 4, r16 = lane & 15;

    f32x4 acc[8][4];
    #pragma unroll
    for (int mt = 0; mt < 8; mt++)
        #pragma unroll
        for (int nt = 0; nt < 4; nt++)
            acc[mt][nt] = (f32x4){0.f, 0.f, 0.f, 0.f};

    const uint4* gA = (const uint4*)(aT + (size_t)ti * 32768);    // 8i x 32h x 128n
    const uint4* gB = (const uint4*)(bT + (size_t)tj * 32768);    // 8j x 32h x 128n

    // ---- stage 1: two K=64 halves; A 32KB @0, B 32KB @32768 ----
    #pragma unroll
    for (int half = 0; half < 2; half++) {
        // async stage: LDS[row][c] = global chunk (c ^ (row&7))  (read undoes XOR)
        #pragma unroll
        for (int t = 0; t < 4; t++) {                    // A: 2048 chunks / 8w / 64l
            int q = w * 256 + t * 64 + lane;
            int row = q >> 3, c = q & 7;
            cp16_async(gA + row * 16 + half * 8 + (c ^ (row & 7)),
                       smem + (q << 4) - (lane << 4));   // wave-uniform base
        }
        #pragma unroll
        for (int t = 0; t < 4; t++) {                    // B: 2048 chunks
            int q = w * 256 + t * 64 + lane;
            int row = q >> 3, c = q & 7;
            cp16_async(gB + row * 16 + half * 8 + (c ^ (row & 7)),
                       smem + 32768 + (q << 4) - (lane << 4));
        }
        __syncthreads();                                  // staging drained here

        #pragma unroll
        for (int ks2 = 0; ks2 < 2; ks2++) {
            int ch = ks2 * 4 + kg;
            bf8_t af[8];
            #pragma unroll
            for (int mt = 0; mt < 8; mt++) {
                int mm = wr * 128 + mt * 16 + r16;
                af[mt] = *(const bf8_t*)(smem + mm * 128 + ((ch ^ (mm & 7)) << 4));
            }
            #pragma unroll
            for (int nt = 0; nt < 4; nt++) {
                int nn = wc * 64 + nt * 16 + r16;
                bf8_t bfr = *(const bf8_t*)(smem + 32768 + nn * 128 +
                                            ((ch ^ (nn & 7)) << 4));
                #pragma unroll
                for (int mt = 0; mt < 8; mt++)
                    acc[mt][nt] = __builtin_amdgcn_mfma_f32_16x16x32_bf16(
                        af[mt], bfr, acc[mt][nt], 0, 0, 0);
            }
        }
        __syncthreads();   // LDS free for next half / the transpose
    }

    // ---- stage 2, single pass ----
    // O2[p][k2]: p = i_loc*8 + j_loc (64 pairs), k2 = (nn&31)*32 + (mm&31)
    // (1024 per row = 2KB). chunk c2 = k2>>3 (0..127);
    // swizzle pc = c2 ^ ((c2>>3)&7) ^ (p&7)  (bijective per p; spreads banks).
    unsigned short* O2b = (unsigned short*)smem;        // 64 x 1024 bf16 = 128 KB
    const int psw = r16 & 7;
    // two W2 fragment streams: z-tiles zg*2 and zg*2+1
    const unsigned short* wz0 = W2 + (size_t)(zg * 2) * 16384 + r16 * 32 + kg * 8;
    const unsigned short* wz1 = wz0 + 16384;

#define W2LDA(x) (*(const bf8_t*)(wz0 + (x) * 512))
#define W2LDB(x) (*(const bf8_t*)(wz1 + (x) * 512))
    // two-stream depth-2 ring preload (16 VGPR): flies under the transpose
    bf8_t w0 = W2LDA(0), w1 = W2LDA(1);
    bf8_t x0 = W2LDB(0), x1 = W2LDB(1);

    // transpose ALL accs -> O2 (acc C/D: row = kg*4+r, col = r16); acc dead after.
    #pragma unroll
    for (int mt = 0; mt < 8; mt++) {
        #pragma unroll
        for (int nt = 0; nt < 4; nt++) {
            int p  = (wr * 4 + (mt >> 1)) * 8 + (wc * 2 + (nt >> 1));
            int k2 = ((nt & 1) * 16 + r16) * 32 + ((mt & 1) << 4) + kg * 4; // +r
            int c2 = k2 >> 3;
            int pc = c2 ^ ((c2 >> 3) & 7) ^ (p & 7);
            *(uint2*)(O2b + p * 1024 + pc * 8 + (k2 & 7)) =
                make_uint2(pack2(acc[mt][nt][0], acc[mt][nt][1]),
                           pack2(acc[mt][nt][2], acc[mt][nt][3]));
        }
    }
    __syncthreads();

    // GEMM: Z[64,128] = O2[64,1024] @ W2[1024,128]; 32 K-chunks, two-stream
    // ring slot = sl & 1, lookahead 2 (stage 2 is NOT latency-bound: R4).
    f32x4 acc2_00 = {0.f,0.f,0.f,0.f}, acc2_01 = {0.f,0.f,0.f,0.f};
    f32x4 acc2_10 = {0.f,0.f,0.f,0.f}, acc2_11 = {0.f,0.f,0.f,0.f};
    // A rows mg*32+r16 (m-tile 0) and +16 (m-tile 1); (row&7)==psw for both.
    const unsigned short* O2r = O2b + (mg * 32 + r16) * 1024;

// Snapshot BEFORE prefetch overwrites the ring regs (v4 lesson). sl literal.
#define S2R(sl, wa, xa, PF)                                                   \
    {                                                                         \
        bf8_t wca = wa, wcb = xa;                                             \
        PF;                                                                   \
        int c2 = (sl) * 4 + kg;                                               \
        int pc = c2 ^ ((c2 >> 3) & 7) ^ psw;                                  \
        const unsigned short* ar = O2r + pc * 8;                              \
        bf8_t a0 = *(const bf8_t*)(ar);                                       \
        bf8_t a1 = *(const bf8_t*)(ar + 16 * 1024);                           \
        acc2_00 = __builtin_amdgcn_mfma_f32_16x16x32_bf16(a0, wca, acc2_00,   \
                                                          0, 0, 0);           \
        acc2_01 = __builtin_amdgcn_mfma_f32_16x16x32_bf16(a0, wcb, acc2_01,   \
                                                          0, 0, 0);           \
        acc2_10 = __builtin_amdgcn_mfma_f32_16x16x32_bf16(a1, wca, acc2_10,   \
                                                          0, 0, 0);           \
        acc2_11 = __builtin_amdgcn_mfma_f32_16x16x32_bf16(a1, wcb, acc2_11,   \
                                                          0, 0, 0);           \
    }

    S2R(0,  w0, x0, { w0 = W2LDA(2);  x0 = W2LDB(2);  })
    S2R(1,  w1, x1, { w1 = W2LDA(3);  x1 = W2LDB(3);  })
    S2R(2,  w0, x0, { w0 = W2LDA(4);  x0 = W2LDB(4);  })
    S2R(3,  w1, x1, { w1 = W2LDA(5);  x1 = W2LDB(5);  })
    S2R(4,  w0, x0, { w0 = W2LDA(6);  x0 = W2LDB(6);  })
    S2R(5,  w1, x1, { w1 = W2LDA(7);  x1 = W2LDB(7);  })
    S2R(6,  w0, x0, { w0 = W2LDA(8);  x0 = W2LDB(8);  })
    S2R(7,  w1, x1, { w1 = W2LDA(9);  x1 = W2LDB(9);  })
    S2R(8,  w0, x0, { w0 = W2LDA(10); x0 = W2LDB(10); })
    S2R(9,  w1, x1, { w1 = W2LDA(11); x1 = W2LDB(11); })
    S2R(10, w0, x0, { w0 = W2LDA(12); x0 = W2LDB(12); })
    S2R(11, w1, x1, { w1 = W2LDA(13); x1 = W2LDB(13); })
    S2R(12, w0, x0, { w0 = W2LDA(14); x0 = W2LDB(14); })
    S2R(13, w1, x1, { w1 = W2LDA(15); x1 = W2LDB(15); })
    S2R(14, w0, x0, { w0 = W2LDA(16); x0 = W2LDB(16); })
    S2R(15, w1, x1, { w1 = W2LDA(17); x1 = W2LDB(17); })
    S2R(16, w0, x0, { w0 = W2LDA(18); x0 = W2LDB(18); })
    S2R(17, w1, x1, { w1 = W2LDA(19); x1 = W2LDB(19); })
    S2R(18, w0, x0, { w0 = W2LDA(20); x0 = W2LDB(20); })
    S2R(19, w1, x1, { w1 = W2LDA(21); x1 = W2LDB(21); })
    S2R(20, w0, x0, { w0 = W2LDA(22); x0 = W2LDB(22); })
    S2R(21, w1, x1, { w1 = W2LDA(23); x1 = W2LDB(23); })
    S2R(22, w0, x0, { w0 = W2LDA(24); x0 = W2LDB(24); })
    S2R(23, w1, x1, { w1 = W2LDA(25); x1 = W2LDB(25); })
    S2R(24, w0, x0, { w0 = W2LDA(26); x0 = W2LDB(26); })
    S2R(25, w1, x1, { w1 = W2LDA(27); x1 = W2LDB(27); })
    S2R(26, w0, x0, { w0 = W2LDA(28); x0 = W2LDB(28); })
    S2R(27, w1, x1, { w1 = W2LDA(29); x1 = W2LDB(29); })
    S2R(28, w0, x0, { w0 = W2LDA(30); x0 = W2LDB(30); })
    S2R(29, w1, x1, { w1 = W2LDA(31); x1 = W2LDB(31); })
    S2R(30, w0, x0, {})
    S2R(31, w1, x1, {})
#undef S2R
#undef W2LDA
#undef W2LDB

    // ---- epilogue: scale by 1/(pair_mask+eps), add bias, store ----
    // acc2_mn: m = pair-tile (rows mg*32+m*16), n = z-tile (z = (zg*2+n)*16+r16)
    const int i0 = ti * 8, j0 = tj * 8;
    const float boz0 = bo[(zg * 2) * 16 + r16];
    const float boz1 = bo[(zg * 2 + 1) * 16 + r16];
    #pragma unroll
    for (int m = 0; m < 2; m++)
        #pragma unroll
        for (int r = 0; r < 4; r++) {
            int p = mg * 32 + m * 16 + kg * 4 + r;
            int i = i0 + (p >> 3), j = j0 + (p & 7);
            float recip = pmr[i * 256 + j];
            size_t o = ((size_t)(i * 256 + j)) * 128;
            float v0 = (m ? acc2_10[r] : acc2_00[r]) * recip + boz0;
            float v1 = (m ? acc2_11[r] : acc2_01[r]) * recip + boz1;
            out[o + (zg * 2) * 16 + r16]     = v0;
            out[o + (zg * 2 + 1) * 16 + r16] = v1;
        }
}

// ---------------------------------------------------------------------------
extern "C" void kernel_launch(void* const* d_in, const int* in_sizes, int n_in,
                              void* d_out, int out_size, void* d_ws, size_t ws_size,
                              hipStream_t stream)
{
    const float* m    = (const float*)d_in[0];
    const float* mask = (const float*)d_in[1];
    const float* gam  = (const float*)d_in[2];
    const float* bet  = (const float*)d_in[3];
    const float* Wa   = (const float*)d_in[4];
    const float* ba   = (const float*)d_in[5];
    const float* Wb   = (const float*)d_in[6];
    const float* bb   = (const float*)d_in[7];
    const float* Wo   = (const float*)d_in[8];
    const float* bo   = (const float*)d_in[9];
    float* out = (float*)d_out;

    unsigned short* aT  = (unsigned short*)d_ws;           // 8192*128 bf16 = 2 MB
    unsigned short* bT  = aT + 8192 * 128;                 // 2 MB
    unsigned short* W2  = bT + 8192 * 128;                 // 128*1024 bf16 = 256 KB
    unsigned short* WTb = W2 + 128 * 1024;                 // 64*256 bf16 = 32 KB
    float* pmr = (float*)(WTb + 64 * 256);                 // 256*256 fp32 = 256 KB

    k_prep   <<<  64, 256, 0, stream>>>(Wa, Wb, WTb);
    k_ln_proj<<<2816, 256, 0, stream>>>(m, mask, gam, bet, WTb, ba, bb, Wo,
                                        aT, bT, W2, pmr);
    k_outer  <<<1024, 512, 0, stream>>>(aT, bT, W2, pmr, bo, out);
}

// Round 11
// 158.496 us; speedup vs baseline: 1.0868x; 1.0566x over previous
//
#include <hip/hip_runtime.h>
#include <hip/hip_bf16.h>

// ---------------------------------------------------------------------------
// OuterProductMean (AlphaFold) fused MFMA implementation for gfx950.
//   B=1, N=128 (MSA depth), L=256, C_M=256, C_H=32, C_Z=128
// Pipeline (3 launches):
//   k_prep    : [Wa|Wb] fp32 -> WT bf16 [64][256] (h-major, c contiguous)
//   k_ln_proj : main blocks: LayerNorm + a/b projection (MFMA) -> aT/bT bf16
//               [8192][128] (row = l*32+h, col = MSA index n -> K-contiguous).
//               tail: W2 = Wo bf16 fragment-sequential; pm_recip.
//   k_outer   : v11 == v6 (FINAL REVERT). 8i x 8j tile (64 pairs/block,
//               grid 1024, 64KB LDS, 1 block/CU), two-kh-half stage 2,
//               depth-8 single-stream W2 ring.
//               Session ledger: v6 = 55.3us clean (WRITE 32768KB). The
//               (32,32) stage-2 retile (v7-v10) verifiably halves stage-2
//               LDS traffic (bank-conflict cycles 5.24M->3.15M) but EVERY
//               variant spilled (+11..36MB scratch writes) regardless of
//               ring depth (64/32/16 VGPR) or phase structure (two-half /
//               single-pass): with acc[8][4]=128 AGPR pinned, the allocator
//               cannot fit any retiled stage-2 schedule in the remaining
//               128 VGPR at source level. Reverted per pre-commitment (R10).
// ---------------------------------------------------------------------------

typedef __attribute__((ext_vector_type(8))) short bf8_t;   // 8 x bf16 (4 VGPRs)
typedef __attribute__((ext_vector_type(4))) float f32x4;   // MFMA accumulator

__device__ __forceinline__ unsigned short f2bf(float f) {
    unsigned int u = __float_as_uint(f);
    u += 0x7fffu + ((u >> 16) & 1u);        // RNE (finite values only)
    return (unsigned short)(u >> 16);
}
__device__ __forceinline__ unsigned int pack2(float a, float b) {
    return (unsigned int)f2bf(a) | ((unsigned int)f2bf(b) << 16);
}

// async 16B global -> LDS (dest = wave-uniform base + lane*16, linear)
__device__ __forceinline__ void cp16_async(const void* g, void* l) {
    __builtin_amdgcn_global_load_lds(
        (const __attribute__((address_space(1))) unsigned int*)g,
        (__attribute__((address_space(3))) unsigned int*)l, 16, 0, 0);
}

// ---------------------------------------------------------------------------
// WT[h][c] = (h<32 ? Wa[c][h] : Wb[c][h-32]), bf16. 16384 elems, 64 blocks.
__global__ __launch_bounds__(256) void k_prep(const float* __restrict__ Wa,
                                              const float* __restrict__ Wb,
                                              unsigned short* __restrict__ WTb) {
    int u = blockIdx.x * 256 + threadIdx.x;          // u = h*256 + c
    int h = u >> 8, c = u & 255;
    float v = (h < 32) ? Wa[c * 32 + h] : Wb[c * 32 + (h - 32)];
    WTb[u] = f2bf(v);
}

// ---------------------------------------------------------------------------
// Blocks [0,2048): LayerNorm + projection. Blocks [2048,2560): W2 build.
// Blocks [2560,2816): pair-mask reciprocal.
__global__ __launch_bounds__(256) void k_ln_proj(
    const float* __restrict__ gm, const float* __restrict__ gmask,
    const float* __restrict__ gamma, const float* __restrict__ beta,
    const unsigned short* __restrict__ WTb,
    const float* __restrict__ ba, const float* __restrict__ bb,
    const float* __restrict__ Wo,
    unsigned short* __restrict__ aT, unsigned short* __restrict__ bT,
    unsigned short* __restrict__ W2, float* __restrict__ pmr)
{
    const int tid = threadIdx.x;
    const int tail = (int)blockIdx.x - 2048;
    if (tail >= 0) {
        if (tail < 512) {
            // W2 fragment-sequential: (zt=z>>4, s=k'>>5, r16=z&15, kg=(k'>>3)&3, e=k'&7)
            // with k' = d*32+c, Wo element index u = (c*32+d)*128 + z.
            int u = tail * 256 + tid;                // u = k*128 + z (coalesced read)
            int k = u >> 7, z = u & 127;
            int c = k >> 5, d = k & 31;
            int kp = d * 32 + c;
            int dst = (((z >> 4) * 32 + (kp >> 5)) * 16 + (z & 15)) * 32
                      + ((kp >> 3) & 3) * 8 + (kp & 7);
            W2[dst] = f2bf(Wo[u]);
        } else {
            int u = (tail - 512) * 256 + tid;        // u = i*256 + j
            int i = u >> 8, j = u & 255;
            float s = 0.f;
            #pragma unroll 8
            for (int n = 0; n < 128; n++)
                s += gmask[n * 256 + i] * gmask[n * 256 + j];
            pmr[u] = 1.f / (s + 1e-8f);
        }
        return;
    }

    __shared__ __align__(16) unsigned short xlb[16 * 256]; // [row][c] bf16, swizzled
    __shared__ float vl[16 * 64];                          // [n-row][h]
    const int lane = tid & 63, w = tid >> 6;
    const int l = blockIdx.x & 255, n0 = ((int)blockIdx.x >> 8) << 4;

    const float4 g4  = ((const float4*)gamma)[lane];
    const float4 be4 = ((const float4*)beta)[lane];

    // ---- phase 1: LN (wave per row, 4 rows per wave) ----
    #pragma unroll
    for (int j = 0; j < 4; j++) {
        int row = w * 4 + j;
        int n = n0 + row;
        float4 v = ((const float4*)(gm + ((size_t)n * 256 + l) * 256))[lane];
        float s = v.x + v.y + v.z + v.w;
        float q = v.x * v.x + v.y * v.y + v.z * v.z + v.w * v.w;
        #pragma unroll
        for (int off = 1; off < 64; off <<= 1) {
            s += __shfl_xor(s, off);
            q += __shfl_xor(q, off);
        }
        float mean = s * (1.f / 256.f);
        float var = fmaxf(q * (1.f / 256.f) - mean * mean, 0.f);
        float rstd = rsqrtf(var + 1e-5f);
        float x0 = (v.x - mean) * rstd * g4.x + be4.x;
        float x1 = (v.y - mean) * rstd * g4.y + be4.y;
        float x2 = (v.z - mean) * rstd * g4.z + be4.z;
        float x3 = (v.w - mean) * rstd * g4.w + be4.w;
        int c8s = lane ^ ((row & 7) << 1);               // 8B-chunk XOR swizzle
        *(uint2*)((char*)xlb + row * 512 + (c8s << 3)) =
            make_uint2(pack2(x0, x1), pack2(x2, x3));
    }
    __syncthreads();

    // ---- phase 2: projection via MFMA (wave w -> h-cols w*16..w*16+15) ----
    const int kg = lane >> 4, r16 = lane & 15;
    const int h = w * 16 + r16;
    f32x4 acc = {0.f, 0.f, 0.f, 0.f};
    #pragma unroll
    for (int ks = 0; ks < 8; ks++) {
        int c8 = ks * 8 + kg * 2;                        // even -> 16B pair intact
        bf8_t af = *(const bf8_t*)((char*)xlb + r16 * 512 +
                                   ((c8 ^ ((r16 & 7) << 1)) << 3));
        bf8_t wf = *(const bf8_t*)(WTb + (size_t)h * 256 + ks * 32 + kg * 8);
        acc = __builtin_amdgcn_mfma_f32_16x16x32_bf16(af, wf, acc, 0, 0, 0);
    }
    float bias = (h < 32) ? ba[h] : bb[h - 32];
    #pragma unroll
    for (int r = 0; r < 4; r++) {
        int nrow = kg * 4 + r;                           // C/D row = MSA row index
        float mk = gmask[(size_t)(n0 + nrow) * 256 + l];
        vl[nrow * 64 + h] = (acc[r] + bias) * mk;
    }
    __syncthreads();

    // ---- phase 3: repack, 8 n-values per thread, 16B stores ----
    if (tid < 128) {
        int row = tid >> 1, half = tid & 1;              // row = h index 0..63
        int hh = row & 31;
        unsigned short* dst = (row < 32) ? aT : bT;
        unsigned int pk[4];
        #pragma unroll
        for (int jj = 0; jj < 4; jj++)
            pk[jj] = pack2(vl[(half * 8 + 2 * jj) * 64 + row],
                           vl[(half * 8 + 2 * jj + 1) * 64 + row]);
        *(uint4*)(dst + ((size_t)l * 32 + hh) * 128 + n0 + half * 8) =
            make_uint4(pk[0], pk[1], pk[2], pk[3]);
    }
}

// ---------------------------------------------------------------------------
// Fused outer-product + Wo projection, v11 == v6 (final).
// Grid 1024 = 32 tj (fast) x 32 ti. 512 thr = 8 waves; 64KB LDS; 1 block/CU.
// Stage 1: 256(i.h) x 256(j.h) outer tile, K=128 in two halves of 64.
//   Wave grid 2(wr) x 4(wc) -> per-wave 128x64 -> acc[8][4] (128 AGPR).
//   Staging: global_load_lds w=16, source pre-swizzled (LDS linear);
//   A 32KB @0 + B 32KB @32768 per half.
// Stage 2: Z[64 pairs,128] = O2[64,1024] @ W2[1024,128] in two k2-halves
//   (O2 half = 64KB LDS). Wave w -> z-tile w (16 z); each W2 fragment feeds
//   4 MFMAs; depth-8 W2 ring runs continuously across both halves.
__global__ __launch_bounds__(512, 2) void k_outer(
    const unsigned short* __restrict__ aT, const unsigned short* __restrict__ bT,
    const unsigned short* __restrict__ W2, const float* __restrict__ pmr,
    const float* __restrict__ bo, float* __restrict__ out)
{
    __shared__ __align__(16) char smem[65536];
    const int tid = threadIdx.x, lane = tid & 63, w = tid >> 6;   // 8 waves
    const int wr = w >> 2, wc = w & 3;                  // 2 x 4 wave grid
    const int tj = blockIdx.x & 31, ti = blockIdx.x >> 5;         // 32 x 32
    const int kg = lane >> 4, r16 = lane & 15;

    f32x4 acc[8][4];
    #pragma unroll
    for (int mt = 0; mt < 8; mt++)
        #pragma unroll
        for (int nt = 0; nt < 4; nt++)
            acc[mt][nt] = (f32x4){0.f, 0.f, 0.f, 0.f};

    const uint4* gA = (const uint4*)(aT + (size_t)ti * 32768);    // 8i x 32h x 128n
    const uint4* gB = (const uint4*)(bT + (size_t)tj * 32768);    // 8j x 32h x 128n

    // ---- stage 1: two K=64 halves; A 32KB @0, B 32KB @32768 ----
    #pragma unroll
    for (int half = 0; half < 2; half++) {
        // async stage: LDS[row][c] = global chunk (c ^ (row&7))  (read undoes XOR)
        #pragma unroll
        for (int t = 0; t < 4; t++) {                    // A: 2048 chunks / 8w / 64l
            int q = w * 256 + t * 64 + lane;
            int row = q >> 3, c = q & 7;
            cp16_async(gA + row * 16 + half * 8 + (c ^ (row & 7)),
                       smem + (q << 4) - (lane << 4));   // wave-uniform base
        }
        #pragma unroll
        for (int t = 0; t < 4; t++) {                    // B: 2048 chunks
            int q = w * 256 + t * 64 + lane;
            int row = q >> 3, c = q & 7;
            cp16_async(gB + row * 16 + half * 8 + (c ^ (row & 7)),
                       smem + 32768 + (q << 4) - (lane << 4));
        }
        __syncthreads();                                  // staging drained here

        #pragma unroll
        for (int ks2 = 0; ks2 < 2; ks2++) {
            int ch = ks2 * 4 + kg;
            bf8_t af[8];
            #pragma unroll
            for (int mt = 0; mt < 8; mt++) {
                int mm = wr * 128 + mt * 16 + r16;
                af[mt] = *(const bf8_t*)(smem + mm * 128 + ((ch ^ (mm & 7)) << 4));
            }
            #pragma unroll
            for (int nt = 0; nt < 4; nt++) {
                int nn = wc * 64 + nt * 16 + r16;
                bf8_t bfr = *(const bf8_t*)(smem + 32768 + nn * 128 +
                                            ((ch ^ (nn & 7)) << 4));
                #pragma unroll
                for (int mt = 0; mt < 8; mt++)
                    acc[mt][nt] = __builtin_amdgcn_mfma_f32_16x16x32_bf16(
                        af[mt], bfr, acc[mt][nt], 0, 0, 0);
            }
        }
        __syncthreads();   // LDS free for next half / the transpose
    }

    // ---- stage 2 in two k2-halves kh: transpose + GEMM vs W2 ----
    // O2h[p][k2h]: p = i_loc*8 + j_loc (64 pairs), k2h = d'*32 + c (512),
    // d' = (nn&31) - kh*16 = r16, c = mm&31. chunk c2h = k2h>>3;
    // swizzle pcs = c2h ^ ((c2h>>3)&7) ^ (p&7).
    unsigned short* O2b = (unsigned short*)smem;        // 64 x 512 bf16 = 64 KB
    f32x4 acc2[4];
    #pragma unroll
    for (int q = 0; q < 4; q++) acc2[q] = (f32x4){0.f, 0.f, 0.f, 0.f};
    const int psw = r16 & 7;
    const unsigned short* wz = W2 + (size_t)w * 16384 + r16 * 32 + kg * 8;

#define W2LD(x) (*(const bf8_t*)(wz + (x) * 512))
    // ring preload (flies during the first transpose)
    bf8_t w0 = W2LD(0), w1 = W2LD(1), w2 = W2LD(2), w3 = W2LD(3);
    bf8_t w4 = W2LD(4), w5 = W2LD(5), w6 = W2LD(6), w7 = W2LD(7);

// Snapshot wreg BEFORE the prefetch overwrites it (v4 lesson). sl literal.
#define S2_ITER(sl, wreg, PF)                                                 \
    {                                                                         \
        bf8_t wcur = wreg;                                                    \
        PF;                                                                   \
        int c2h = (sl) * 4 + kg;                                              \
        int pcs = c2h ^ ((c2h >> 3) & 7) ^ psw;                               \
        const unsigned short* ar = O2b + r16 * 512 + pcs * 8;                 \
        bf8_t a0 = *(const bf8_t*)(ar);                                       \
        bf8_t a1 = *(const bf8_t*)(ar + 16 * 512);                            \
        bf8_t a2 = *(const bf8_t*)(ar + 32 * 512);                            \
        bf8_t a3 = *(const bf8_t*)(ar + 48 * 512);                            \
        acc2[0] = __builtin_amdgcn_mfma_f32_16x16x32_bf16(a0, wcur, acc2[0],  \
                                                          0, 0, 0);           \
        acc2[1] = __builtin_amdgcn_mfma_f32_16x16x32_bf16(a1, wcur, acc2[1],  \
                                                          0, 0, 0);           \
        acc2[2] = __builtin_amdgcn_mfma_f32_16x16x32_bf16(a2, wcur, acc2[2],  \
                                                          0, 0, 0);           \
        acc2[3] = __builtin_amdgcn_mfma_f32_16x16x32_bf16(a3, wcur, acc2[3],  \
                                                          0, 0, 0);           \
    }

    #pragma unroll
    for (int kh = 0; kh < 2; kh++) {
        if (kh) __syncthreads();                         // stage2(kh=0) readers done

        // transpose accs with (nt&1)==kh into O2h (acc C/D: row=kg*4+r, col=r16)
        #pragma unroll
        for (int mt = 0; mt < 8; mt++) {
            #pragma unroll
            for (int ntt = 0; ntt < 2; ntt++) {
                int nt = ntt * 2 + kh;
                int p  = (wr * 4 + (mt >> 1)) * 8 + (wc * 2 + ntt);
                int k2h = r16 * 32 + ((mt & 1) << 4) + kg * 4;   // +r in-chunk
                int c2h = k2h >> 3;
                int pcs = c2h ^ ((c2h >> 3) & 7) ^ (p & 7);
                *(uint2*)(O2b + p * 512 + pcs * 8 + (k2h & 7)) =
                    make_uint2(pack2(acc[mt][nt][0], acc[mt][nt][1]),
                               pack2(acc[mt][nt][2], acc[mt][nt][3]));
            }
        }
        __syncthreads();

        // GEMM: 16 K-chunks of this half; ring slot = s_glob & 7.
        S2_ITER(0,  w0, if (kh == 0 || 0  < 8) w0 = W2LD(kh * 16 + 8))
        S2_ITER(1,  w1, if (kh == 0 || 1  < 8) w1 = W2LD(kh * 16 + 9))
        S2_ITER(2,  w2, if (kh == 0 || 2  < 8) w2 = W2LD(kh * 16 + 10))
        S2_ITER(3,  w3, if (kh == 0 || 3  < 8) w3 = W2LD(kh * 16 + 11))
        S2_ITER(4,  w4, if (kh == 0 || 4  < 8) w4 = W2LD(kh * 16 + 12))
        S2_ITER(5,  w5, if (kh == 0 || 5  < 8) w5 = W2LD(kh * 16 + 13))
        S2_ITER(6,  w6, if (kh == 0 || 6  < 8) w6 = W2LD(kh * 16 + 14))
        S2_ITER(7,  w7, if (kh == 0 || 7  < 8) w7 = W2LD(kh * 16 + 15))
        S2_ITER(8,  w0, if (kh == 0) w0 = W2LD(16))
        S2_ITER(9,  w1, if (kh == 0) w1 = W2LD(17))
        S2_ITER(10, w2, if (kh == 0) w2 = W2LD(18))
        S2_ITER(11, w3, if (kh == 0) w3 = W2LD(19))
        S2_ITER(12, w4, if (kh == 0) w4 = W2LD(20))
        S2_ITER(13, w5, if (kh == 0) w5 = W2LD(21))
        S2_ITER(14, w6, if (kh == 0) w6 = W2LD(22))
        S2_ITER(15, w7, if (kh == 0) w7 = W2LD(23))
    }
#undef S2_ITER
#undef W2LD

    // ---- epilogue: scale by 1/(pair_mask+eps), add bias, store ----
    const int i0 = ti * 8, j0 = tj * 8;
    const int z = w * 16 + r16;
    const float boz = bo[z];
    #pragma unroll
    for (int q = 0; q < 4; q++)
        #pragma unroll
        for (int r = 0; r < 4; r++) {
            int p = q * 16 + kg * 4 + r;                 // pair = C/D row + tile
            int i = i0 + (p >> 3), j = j0 + (p & 7);
            float recip = pmr[i * 256 + j];
            out[((size_t)(i * 256 + j)) * 128 + z] = acc2[q][r] * recip + boz;
        }
}

// ---------------------------------------------------------------------------
extern "C" void kernel_launch(void* const* d_in, const int* in_sizes, int n_in,
                              void* d_out, int out_size, void* d_ws, size_t ws_size,
                              hipStream_t stream)
{
    const float* m    = (const float*)d_in[0];
    const float* mask = (const float*)d_in[1];
    const float* gam  = (const float*)d_in[2];
    const float* bet  = (const float*)d_in[3];
    const float* Wa   = (const float*)d_in[4];
    const float* ba   = (const float*)d_in[5];
    const float* Wb   = (const float*)d_in[6];
    const float* bb   = (const float*)d_in[7];
    const float* Wo   = (const float*)d_in[8];
    const float* bo   = (const float*)d_in[9];
    float* out = (float*)d_out;

    unsigned short* aT  = (unsigned short*)d_ws;           // 8192*128 bf16 = 2 MB
    unsigned short* bT  = aT + 8192 * 128;                 // 2 MB
    unsigned short* W2  = bT + 8192 * 128;                 // 128*1024 bf16 = 256 KB
    unsigned short* WTb = W2 + 128 * 1024;                 // 64*256 bf16 = 32 KB
    float* pmr = (float*)(WTb + 64 * 256);                 // 256*256 fp32 = 256 KB

    k_prep   <<<  64, 256, 0, stream>>>(Wa, Wb, WTb);
    k_ln_proj<<<2816, 256, 0, stream>>>(m, mask, gam, bet, WTb, ba, bb, Wo,
                                        aT, bT, W2, pmr);
    k_outer  <<<1024, 512, 0, stream>>>(aT, bT, W2, pmr, bo, out);
}